// Round 9
// baseline (432.327 us; speedup 1.0000x reference)
//
#include <hip/hip_runtime.h>
#include <math.h>

#define NN   100000
#define EE   1600000
#define FIN  256
#define NCLS 16
#define NEG  0.2f

#define NEDGE (EE + NN)     // with self-loops
#define WBKT  256           // dsts per bucket
#define NBKT  ((NN + WBKT - 1) / WBKT)   // 391
#define CAP   5120          // per-bucket capacity (mean 4352)
#define ABLK  4096          // edges per binA block
#define NABLK ((NEDGE + ABLK - 1) / ABLK)  // 416

#define NSLC 4              // channel slices of 16 ch (= 2 heads) each
// per-slice gather footprint: h1b 3.2MB + al 0.8MB = 4.0MB ~ one XCD L2

// ---- workspace layout (4-byte element offsets) ----
#define OFF_GCNT  0                          // [392] zeroed each call
#define OFF_BASE  392                        // [392]
#define OFF_ROW   784                        // [NN+1]
#define OFF_BKT   100788                     // [NBKT*CAP] packed (src<<8)|dlow
#define OFF_ADJ   (OFF_BKT + NBKT*CAP)       // [NEDGE]
#define OFF_H1B   (OFF_ADJ + NEDGE)          // [NSLC][NN][8] u32 (2xbf16) SLICED pre-attn values
#define OFF_H1E   (OFF_H1B + NN*32)          // [NSLC][NN][8] u32 (2xbf16) SLICED post-ELU
#define OFF_AL1S  (OFF_H1E + NN*32)          // [NSLC][NN][2] f32 SLICED src logits (head pairs)
#define OFF_AL1D  (OFF_AL1S + NN*8)          // [NN*8] f32 dst logits (dense)
#define OFF_H2B   (OFF_AL1D + NN*8)          // [NN*16] bf16
#define OFF_AL2S  (OFF_H2B + NN*8)           // [NN]
#define OFF_AL2D  (OFF_AL2S + NN)            // [NN]

__device__ __forceinline__ float lrelu(float x) { return x >= 0.f ? x : NEG * x; }
__device__ __forceinline__ unsigned short f2bf(float x) {
    unsigned u = __float_as_uint(x);
    return (unsigned short)((u + 0x7FFF + ((u >> 16) & 1)) >> 16);   // RNE
}
__device__ __forceinline__ float bf2f(unsigned short b) {
    return __uint_as_float(((unsigned)b) << 16);
}
__device__ __forceinline__ float bflo(unsigned u) { return __uint_as_float(u << 16); }
__device__ __forceinline__ float bfhi(unsigned u) { return __uint_as_float(u & 0xFFFF0000u); }

// ---------- CSR build, phase A: bin edges by dst>>8 ----------
__global__ __launch_bounds__(256) void k_binA(
    const int* __restrict__ esrc, const int* __restrict__ edst,
    int* __restrict__ gcnt, unsigned* __restrict__ bkt)
{
    __shared__ int lcnt[NBKT];
    __shared__ int lbase[NBKT];
    const int t = threadIdx.x;
    const int e0 = blockIdx.x * ABLK;
    for (int i = t; i < NBKT; i += 256) lcnt[i] = 0;
    __syncthreads();

    unsigned wrd[16];
    unsigned short bb[16], ll[16];
    #pragma unroll
    for (int j = 0; j < 16; ++j) {
        int ei = e0 + j * 256 + t;
        bb[j] = 0xFFFFu;
        if (ei < NEDGE) {
            int s, d;
            if (ei < EE) { s = esrc[ei]; d = edst[ei]; } else { s = d = ei - EE; }
            int b = d >> 8;
            wrd[j] = ((unsigned)s << 8) | (unsigned)(d & 255);
            bb[j] = (unsigned short)b;
            ll[j] = (unsigned short)atomicAdd(&lcnt[b], 1);
        }
    }
    __syncthreads();
    for (int i = t; i < NBKT; i += 256)
        lbase[i] = lcnt[i] ? atomicAdd(&gcnt[i], lcnt[i]) : 0;
    __syncthreads();
    #pragma unroll
    for (int j = 0; j < 16; ++j) {
        if (bb[j] != 0xFFFFu) {
            int b = bb[j];
            bkt[(size_t)b * CAP + lbase[b] + ll[j]] = wrd[j];
        }
    }
}

// ---------- CSR build, phase B: scan bucket counts -> bases ----------
__global__ __launch_bounds__(512) void k_scanB(
    const int* __restrict__ gcnt, int* __restrict__ base, int* __restrict__ row)
{
    __shared__ int s[512];
    int t = threadIdx.x;
    int v = (t < NBKT) ? gcnt[t] : 0;
    s[t] = v;
    __syncthreads();
    for (int off = 1; off < 512; off <<= 1) {
        int u = (t >= off) ? s[t - off] : 0;
        __syncthreads();
        s[t] += u;
        __syncthreads();
    }
    if (t <= NBKT) base[t] = s[t] - v;   // exclusive; base[NBKT] = NEDGE
    if (t == 0) row[NN] = NEDGE;
}

// ---------- CSR build, phase C: per-bucket local sort -> row + adj ----------
__global__ __launch_bounds__(256) void k_binC(
    const int* __restrict__ gcnt, const int* __restrict__ base,
    const unsigned* __restrict__ bkt, int* __restrict__ row, int* __restrict__ adj)
{
    __shared__ unsigned wd[CAP];          // 20 KB stage
    __shared__ int hist[256], pref[256], cnt2[256];
    const int g = blockIdx.x, t = threadIdx.x;
    const int cn = gcnt[g], bs = base[g];
    hist[t] = 0; cnt2[t] = 0;
    __syncthreads();
    for (int i = t; i < cn; i += 256) {
        unsigned w = bkt[(size_t)g * CAP + i];
        wd[i] = w;
        atomicAdd(&hist[w & 255], 1);
    }
    __syncthreads();
    int v = hist[t];
    pref[t] = v;
    __syncthreads();
    for (int off = 1; off < 256; off <<= 1) {
        int u = (t >= off) ? pref[t - off] : 0;
        __syncthreads();
        pref[t] += u;
        __syncthreads();
    }
    int ex = pref[t] - v;                 // exclusive local prefix
    int n = g * 256 + t;
    if (n < NN) row[n] = bs + ex;
    pref[t] = ex;
    __syncthreads();
    for (int i = t; i < cn; i += 256) {
        unsigned w = wd[i];
        int dl = w & 255;
        int p = atomicAdd(&cnt2[dl], 1);
        adj[bs + pref[dl] + p] = (int)(w >> 8);
    }
}

// ---------- layer 1 GEMM: 64x64 tile; SLICED bf16 value output ----------
__global__ __launch_bounds__(256) void k_gemm1(
    const float* __restrict__ x, const float* __restrict__ W1,
    const float* __restrict__ a1s, const float* __restrict__ a1d,
    unsigned* __restrict__ h1bS, float* __restrict__ alS, float* __restrict__ al1d)
{
    __shared__ float sxT[32][68];
    __shared__ float sW[32][64];
    const int t = threadIdx.x;
    const int n0 = blockIdx.x * 64;
    const int tr = t >> 4, tc = t & 15;

    float acc[4][4] = {};

    for (int kc = 0; kc < 256; kc += 32) {
        __syncthreads();
        #pragma unroll
        for (int it = 0; it < 2; ++it) {
            int i = t + it * 256;
            int r = i >> 3, fj = i & 7;
            int n = n0 + r;
            float4 v = (n < NN) ? *(const float4*)(x + (size_t)n * FIN + kc + fj * 4)
                                : make_float4(0.f, 0.f, 0.f, 0.f);
            sxT[fj * 4 + 0][r] = v.x;
            sxT[fj * 4 + 1][r] = v.y;
            sxT[fj * 4 + 2][r] = v.z;
            sxT[fj * 4 + 3][r] = v.w;
        }
        #pragma unroll
        for (int it = 0; it < 2; ++it) {
            int i = t + it * 256;
            int r = i >> 4, fj = i & 15;
            *(float4*)&sW[r][fj * 4] = *(const float4*)(W1 + (size_t)(kc + r) * 64 + fj * 4);
        }
        __syncthreads();
        #pragma unroll
        for (int k = 0; k < 32; ++k) {
            float4 a = *(const float4*)&sxT[k][tr * 4];
            float4 b = *(const float4*)&sW[k][tc * 4];
            acc[0][0] += a.x * b.x; acc[0][1] += a.x * b.y; acc[0][2] += a.x * b.z; acc[0][3] += a.x * b.w;
            acc[1][0] += a.y * b.x; acc[1][1] += a.y * b.y; acc[1][2] += a.y * b.z; acc[1][3] += a.y * b.w;
            acc[2][0] += a.z * b.x; acc[2][1] += a.z * b.y; acc[2][2] += a.z * b.z; acc[2][3] += a.z * b.w;
            acc[3][0] += a.w * b.x; acc[3][1] += a.w * b.y; acc[3][2] += a.w * b.z; acc[3][3] += a.w * b.w;
        }
    }

    // sliced store: thread tc covers channels tc*4..tc*4+3 -> slice cb = tc>>2,
    // within-slice u32 pair at (tc&3)*2
    const int cb = tc >> 2;
    #pragma unroll
    for (int j = 0; j < 4; ++j) {
        int n = n0 + tr * 4 + j;
        if (n < NN) {
            uint2 o;
            o.x = (unsigned)f2bf(acc[j][0]) | ((unsigned)f2bf(acc[j][1]) << 16);
            o.y = (unsigned)f2bf(acc[j][2]) | ((unsigned)f2bf(acc[j][3]) << 16);
            *(uint2*)(h1bS + ((size_t)cb * NN + n) * 8 + (tc & 3) * 2) = o;
        }
    }

    float sa[4], da[4];
    #pragma unroll
    for (int u = 0; u < 4; ++u) { sa[u] = a1s[tc * 4 + u]; da[u] = a1d[tc * 4 + u]; }
    #pragma unroll
    for (int j = 0; j < 4; ++j) {
        float vs = acc[j][0] * sa[0] + acc[j][1] * sa[1] + acc[j][2] * sa[2] + acc[j][3] * sa[3];
        float vd = acc[j][0] * da[0] + acc[j][1] * da[1] + acc[j][2] * da[2] + acc[j][3] * da[3];
        vs += __shfl_xor(vs, 1, 64);
        vd += __shfl_xor(vd, 1, 64);
        int n = n0 + tr * 4 + j;
        if (!(tc & 1) && n < NN) {
            int hh = tc >> 1;                   // head 0..7
            alS[((size_t)(hh >> 1) * NN + n) * 2 + (hh & 1)] = vs;  // sliced head-pair
            al1d[n * 8 + hh] = vd;
        }
    }
}

// ---------- layer 1 aggregation, CHANNEL-SLICED, L2-pinned ----------
// Slice p = blockIdx&3 (chans p*16..p*16+15 = heads 2p,2p+1): with round-robin
// blockIdx->XCD dispatch, slice p runs on XCDs {p,p+4}; its 3.2MB h1bS slice +
// 0.8MB alS slice stay L2-resident (R8 measured the pinning: FETCH 252->91MB).
// Each 8-lane group owns one dst: walks the FULL adjacency (17 edges mean,
// unroll 4 -> 12 loads in flight), computes its own denominator (2x redundant
// exp), writes final biased+ELU'd channels. No partials, no combine kernel.
__global__ __launch_bounds__(256) void k_agg1c(
    const int* __restrict__ row, const int* __restrict__ adj,
    const float* __restrict__ alS, const float* __restrict__ al1d,
    const unsigned* __restrict__ h1bS, const float* __restrict__ b1,
    unsigned* __restrict__ h1eS)
{
    const int p  = blockIdx.x & 3;            // channel slice
    const int dq = blockIdx.x >> 2;           // 0..NN/32-1
    const int wv = threadIdx.x >> 6, lane = threadIdx.x & 63;
    const int g  = lane >> 3;                 // group (dst) within wave
    const int c  = lane & 7;                  // channel pair within slice
    const int n  = dq * 32 + wv * 8 + g;
    const int hsel = c >> 2;                  // head within slice (0/1)
    const float ald = al1d[n * 8 + p * 2 + hsel];
    const int r0 = row[n], r1 = row[n + 1];
    const float*    alSp = alS + (size_t)p * NN * 2 + hsel;
    const unsigned* hp   = h1bS + (size_t)p * NN * 8 + c;

    float dsum = 0.f, ax = 0.f, ay = 0.f;
    int k = r0;
    for (; k + 3 < r1; k += 4) {
        int s0 = __builtin_nontemporal_load(adj + k);
        int s1 = __builtin_nontemporal_load(adj + k + 1);
        int s2 = __builtin_nontemporal_load(adj + k + 2);
        int s3 = __builtin_nontemporal_load(adj + k + 3);
        float a0 = alSp[s0 * 2], a1 = alSp[s1 * 2];
        float a2 = alSp[s2 * 2], a3 = alSp[s3 * 2];
        unsigned u0 = hp[s0 * 8], u1 = hp[s1 * 8];
        unsigned u2 = hp[s2 * 8], u3 = hp[s3 * 8];
        float w0 = __expf(lrelu(a0 + ald));
        float w1 = __expf(lrelu(a1 + ald));
        float w2 = __expf(lrelu(a2 + ald));
        float w3 = __expf(lrelu(a3 + ald));
        dsum += (w0 + w1) + (w2 + w3);
        ax += w0 * bflo(u0) + w1 * bflo(u1) + w2 * bflo(u2) + w3 * bflo(u3);
        ay += w0 * bfhi(u0) + w1 * bfhi(u1) + w2 * bfhi(u2) + w3 * bfhi(u3);
    }
    for (; k < r1; ++k) {
        int s0 = __builtin_nontemporal_load(adj + k);
        float w0 = __expf(lrelu(alSp[s0 * 2] + ald));
        unsigned u0 = hp[s0 * 8];
        dsum += w0;
        ax += w0 * bflo(u0);
        ay += w0 * bfhi(u0);
    }
    float inv = 1.f / dsum;
    float vx = ax * inv + b1[p * 16 + c * 2];
    float vy = ay * inv + b1[p * 16 + c * 2 + 1];
    vx = vx > 0.f ? vx : __expf(vx) - 1.f;   // ELU fused
    vy = vy > 0.f ? vy : __expf(vy) - 1.f;
    __builtin_nontemporal_store(
        (unsigned)f2bf(vx) | ((unsigned)f2bf(vy) << 16),
        h1eS + ((size_t)p * NN + n) * 8 + c);
}

// ---------- layer 2 GEMM: h2b = bf16(h1e @ W2) from SLICED h1e ----------
__global__ __launch_bounds__(256) void k_gemm2(
    const unsigned short* __restrict__ h1eS16, const float* __restrict__ W2,
    const float* __restrict__ a2s, const float* __restrict__ a2d,
    unsigned short* __restrict__ h2b, float* __restrict__ al2s, float* __restrict__ al2d)
{
    __shared__ float sW[64 * 16];
    const int t = threadIdx.x;
    for (int i = t; i < 64 * 16; i += 256) sW[i] = W2[i];
    __syncthreads();
    const int n = blockIdx.x * 16 + (t >> 4);
    const int k = t & 15;
    if (n >= NN) return;
    float acc = 0.f;
    #pragma unroll
    for (int cb = 0; cb < 4; ++cb) {
        const unsigned short* hr = h1eS16 + ((size_t)cb * NN + n) * 16;
        #pragma unroll
        for (int c = 0; c < 16; ++c)
            acc += bf2f(hr[c]) * sW[(cb * 16 + c) * 16 + k];
    }
    h2b[(size_t)n * 16 + k] = f2bf(acc);
    float vs = acc * a2s[k], vd = acc * a2d[k];
    #pragma unroll
    for (int off = 1; off < 16; off <<= 1) {
        vs += __shfl_xor(vs, off, 64);
        vd += __shfl_xor(vd, off, 64);
    }
    if (k == 0) { al2s[n] = vs; al2d[n] = vd; }
}

// ---------- layer 2 aggregation: 16 edges x 4 lanes, uint2 value loads ----------
__global__ __launch_bounds__(256) void k_agg2(
    const int* __restrict__ row, const int* __restrict__ adj,
    const float* __restrict__ al2s, const float* __restrict__ al2d,
    const unsigned* __restrict__ h2b2, const float* __restrict__ b2,
    float* __restrict__ out)
{
    const int wv = threadIdx.x >> 6, lane = threadIdx.x & 63;
    const int n = blockIdx.x * 4 + wv;
    const float ald = al2d[n];
    const int r0 = row[n], r1 = row[n + 1];

    const int j = lane >> 2;    // edge slot 0..15
    const int r = lane & 3;     // channel quad -> channels 4r..4r+3
    float dsum = 0.f, ax = 0.f, ay = 0.f, bx = 0.f, by = 0.f;
    for (int i = r0; i < r1; i += 16) {
        int i0 = i + j;
        bool act = i0 < r1;
        int s = adj[act ? i0 : r0];
        float w = act ? __expf(lrelu(al2s[s] + ald)) : 0.f;
        uint2 u = *(const uint2*)(h2b2 + s * 8 + r * 2);
        dsum += w;
        ax += w * bflo(u.x);
        ay += w * bfhi(u.x);
        bx += w * bflo(u.y);
        by += w * bfhi(u.y);
    }
    #pragma unroll
    for (int off = 4; off < 64; off <<= 1) {
        dsum += __shfl_xor(dsum, off, 64);
        ax   += __shfl_xor(ax,   off, 64);
        ay   += __shfl_xor(ay,   off, 64);
        bx   += __shfl_xor(bx,   off, 64);
        by   += __shfl_xor(by,   off, 64);
    }
    float inv = 1.f / dsum;
    float v0 = ax * inv + b2[r * 4 + 0];
    float v1 = ay * inv + b2[r * 4 + 1];
    float v2 = bx * inv + b2[r * 4 + 2];
    float v3 = by * inv + b2[r * 4 + 3];

    // log_softmax over 16 channels = 4 lanes x 4
    float mx = fmaxf(fmaxf(v0, v1), fmaxf(v2, v3));
    mx = fmaxf(mx, __shfl_xor(mx, 1, 64));
    mx = fmaxf(mx, __shfl_xor(mx, 2, 64));
    float se = __expf(v0 - mx) + __expf(v1 - mx) + __expf(v2 - mx) + __expf(v3 - mx);
    se += __shfl_xor(se, 1, 64);
    se += __shfl_xor(se, 2, 64);
    float ls = mx + __logf(se);
    if (j == 0)
        *(float4*)(out + (size_t)n * 16 + r * 4) = make_float4(v0 - ls, v1 - ls, v2 - ls, v3 - ls);
}

extern "C" void kernel_launch(void* const* d_in, const int* in_sizes, int n_in,
                              void* d_out, int out_size, void* d_ws, size_t ws_size,
                              hipStream_t stream)
{
    const float* x    = (const float*)d_in[0];
    const int*   eidx = (const int*)d_in[1];
    const float* W1   = (const float*)d_in[2];
    const float* a1s  = (const float*)d_in[3];
    const float* a1d  = (const float*)d_in[4];
    const float* b1   = (const float*)d_in[5];
    const float* W2   = (const float*)d_in[6];
    const float* a2s  = (const float*)d_in[7];
    const float* a2d  = (const float*)d_in[8];
    const float* b2   = (const float*)d_in[9];
    float* out = (float*)d_out;
    float* ws  = (float*)d_ws;

    const int* esrc = eidx;
    const int* edst = eidx + EE;

    int* gcnt = (int*)(ws + OFF_GCNT);
    int* base = (int*)(ws + OFF_BASE);
    int* row  = (int*)(ws + OFF_ROW);
    unsigned* bkt = (unsigned*)(ws + OFF_BKT);
    int* adj  = (int*)(ws + OFF_ADJ);
    unsigned* h1bS = (unsigned*)(ws + OFF_H1B);
    unsigned* h1eS = (unsigned*)(ws + OFF_H1E);
    float* alS   = ws + OFF_AL1S;
    float* al1d  = ws + OFF_AL1D;
    unsigned short* h2b = (unsigned short*)(ws + OFF_H2B);
    float* al2s  = ws + OFF_AL2S;
    float* al2d  = ws + OFF_AL2D;

    hipMemsetAsync(gcnt, 0, 392 * sizeof(int), stream);

    k_binA <<<NABLK, 256, 0, stream>>>(esrc, edst, gcnt, bkt);
    k_scanB<<<1,     512, 0, stream>>>(gcnt, base, row);
    k_binC <<<NBKT,  256, 0, stream>>>(gcnt, base, bkt, row, adj);

    k_gemm1<<<(NN + 63) / 64, 256, 0, stream>>>(x, W1, a1s, a1d, h1bS, alS, al1d);
    k_agg1c<<<(NN / 32) * NSLC, 256, 0, stream>>>(row, adj, alS, al1d, h1bS, b1, h1eS);
    k_gemm2<<<NN / 16, 256, 0, stream>>>((const unsigned short*)h1eS, W2, a2s, a2d, h2b, al2s, al2d);
    k_agg2 <<<NN / 4, 256, 0, stream>>>(row, adj, al2s, al2d, (const unsigned*)h2b, b2, out);
}

// Round 10
// 377.697 us; speedup vs baseline: 1.1446x; 1.1446x over previous
//
#include <hip/hip_runtime.h>
#include <math.h>

#define NN   100000
#define EE   1600000
#define FIN  256
#define NCLS 16
#define NEG  0.2f

#define NEDGE (EE + NN)     // with self-loops
#define WBKT  256           // dsts per bucket
#define NBKT  ((NN + WBKT - 1) / WBKT)   // 391
#define CAP   5120          // per-bucket capacity (mean 4352)
#define ABLK  4096          // edges per binA block
#define NABLK ((NEDGE + ABLK - 1) / ABLK)  // 416

// ---- workspace layout (4-byte element offsets) ----
#define OFF_GCNT  0                          // [392] zeroed each call
#define OFF_BASE  392                        // [392]
#define OFF_ROW   784                        // [NN+1]
#define OFF_BKT   100788                     // [NBKT*CAP] packed (src<<8)|dlow
#define OFF_ADJ   (OFF_BKT + NBKT*CAP)       // [NEDGE]
#define OFF_H1B   (OFF_ADJ + NEDGE)          // [NN*64] bf16 (pre-attn values)
#define OFF_H1E   (OFF_H1B + NN*32)          // [NN*64] bf16 (post-ELU)
#define OFF_AL1S  (OFF_H1E + NN*32)          // [NN*8]
#define OFF_AL1D  (OFF_AL1S + NN*8)          // [NN*8]
#define OFF_H2B   (OFF_AL1D + NN*8)          // [NN*16] bf16
#define OFF_AL2S  (OFF_H2B + NN*8)           // [NN]
#define OFF_AL2D  (OFF_AL2S + NN)            // [NN]

__device__ __forceinline__ float lrelu(float x) { return x >= 0.f ? x : NEG * x; }
__device__ __forceinline__ unsigned short f2bf(float x) {
    unsigned u = __float_as_uint(x);
    return (unsigned short)((u + 0x7FFF + ((u >> 16) & 1)) >> 16);   // RNE
}
__device__ __forceinline__ float bf2f(unsigned short b) {
    return __uint_as_float(((unsigned)b) << 16);
}
__device__ __forceinline__ float bflo(unsigned u) { return __uint_as_float(u << 16); }
__device__ __forceinline__ float bfhi(unsigned u) { return __uint_as_float(u & 0xFFFF0000u); }

// ---------- CSR build, phase A: bin edges by dst>>8 ----------
__global__ __launch_bounds__(256) void k_binA(
    const int* __restrict__ esrc, const int* __restrict__ edst,
    int* __restrict__ gcnt, unsigned* __restrict__ bkt)
{
    __shared__ int lcnt[NBKT];
    __shared__ int lbase[NBKT];
    const int t = threadIdx.x;
    const int e0 = blockIdx.x * ABLK;
    for (int i = t; i < NBKT; i += 256) lcnt[i] = 0;
    __syncthreads();

    unsigned wrd[16];
    unsigned short bb[16], ll[16];
    #pragma unroll
    for (int j = 0; j < 16; ++j) {
        int ei = e0 + j * 256 + t;
        bb[j] = 0xFFFFu;
        if (ei < NEDGE) {
            int s, d;
            if (ei < EE) { s = esrc[ei]; d = edst[ei]; } else { s = d = ei - EE; }
            int b = d >> 8;
            wrd[j] = ((unsigned)s << 8) | (unsigned)(d & 255);
            bb[j] = (unsigned short)b;
            ll[j] = (unsigned short)atomicAdd(&lcnt[b], 1);
        }
    }
    __syncthreads();
    for (int i = t; i < NBKT; i += 256)
        lbase[i] = lcnt[i] ? atomicAdd(&gcnt[i], lcnt[i]) : 0;
    __syncthreads();
    #pragma unroll
    for (int j = 0; j < 16; ++j) {
        if (bb[j] != 0xFFFFu) {
            int b = bb[j];
            bkt[(size_t)b * CAP + lbase[b] + ll[j]] = wrd[j];
        }
    }
}

// ---------- CSR build, phase B: scan bucket counts -> bases ----------
__global__ __launch_bounds__(512) void k_scanB(
    const int* __restrict__ gcnt, int* __restrict__ base, int* __restrict__ row)
{
    __shared__ int s[512];
    int t = threadIdx.x;
    int v = (t < NBKT) ? gcnt[t] : 0;
    s[t] = v;
    __syncthreads();
    for (int off = 1; off < 512; off <<= 1) {
        int u = (t >= off) ? s[t - off] : 0;
        __syncthreads();
        s[t] += u;
        __syncthreads();
    }
    if (t <= NBKT) base[t] = s[t] - v;   // exclusive; base[NBKT] = NEDGE
    if (t == 0) row[NN] = NEDGE;
}

// ---------- CSR build, phase C: per-bucket local sort -> row + adj ----------
__global__ __launch_bounds__(256) void k_binC(
    const int* __restrict__ gcnt, const int* __restrict__ base,
    const unsigned* __restrict__ bkt, int* __restrict__ row, int* __restrict__ adj)
{
    __shared__ unsigned wd[CAP];          // 20 KB stage
    __shared__ int hist[256], pref[256], cnt2[256];
    const int g = blockIdx.x, t = threadIdx.x;
    const int cn = gcnt[g], bs = base[g];
    hist[t] = 0; cnt2[t] = 0;
    __syncthreads();
    for (int i = t; i < cn; i += 256) {
        unsigned w = bkt[(size_t)g * CAP + i];
        wd[i] = w;
        atomicAdd(&hist[w & 255], 1);
    }
    __syncthreads();
    int v = hist[t];
    pref[t] = v;
    __syncthreads();
    for (int off = 1; off < 256; off <<= 1) {
        int u = (t >= off) ? pref[t - off] : 0;
        __syncthreads();
        pref[t] += u;
        __syncthreads();
    }
    int ex = pref[t] - v;                 // exclusive local prefix
    int n = g * 256 + t;
    if (n < NN) row[n] = bs + ex;
    pref[t] = ex;
    __syncthreads();
    for (int i = t; i < cn; i += 256) {
        unsigned w = wd[i];
        int dl = w & 255;
        int p = atomicAdd(&cnt2[dl], 1);
        adj[bs + pref[dl] + p] = (int)(w >> 8);
    }
}

// ---------- layer 1 GEMM: 64x64 tile, 4x4 register tile; bf16 value output ----------
// Register-prefetch double buffering: next K-step's x/W tiles are loaded into
// registers BEFORE the current compute, hiding global latency under the FMAs.
__global__ __launch_bounds__(256) void k_gemm1(
    const float* __restrict__ x, const float* __restrict__ W1,
    const float* __restrict__ a1s, const float* __restrict__ a1d,
    unsigned short* __restrict__ h1b, float* __restrict__ al1s, float* __restrict__ al1d)
{
    __shared__ float sxT[32][68];
    __shared__ float sW[32][64];
    const int t = threadIdx.x;
    const int n0 = blockIdx.x * 64;
    const int tr = t >> 4, tc = t & 15;

    // per-thread load coordinates
    const int xr0 = t >> 3,        xf0 = t & 7;          // it=0 x
    const int xr1 = (t + 256) >> 3, xf1 = (t + 256) & 7; // it=1 x
    const int wr0 = t >> 4,        wf0 = t & 15;         // it=0 W
    const int wr1 = (t + 256) >> 4, wf1 = (t + 256) & 15;// it=1 W
    const int nx0 = n0 + xr0, nx1 = n0 + xr1;

    float acc[4][4] = {};
    float4 px0, px1, pw0, pw1;

    // prefetch kc = 0
    px0 = (nx0 < NN) ? *(const float4*)(x + (size_t)nx0 * FIN + xf0 * 4)
                     : make_float4(0.f, 0.f, 0.f, 0.f);
    px1 = (nx1 < NN) ? *(const float4*)(x + (size_t)nx1 * FIN + xf1 * 4)
                     : make_float4(0.f, 0.f, 0.f, 0.f);
    pw0 = *(const float4*)(W1 + (size_t)wr0 * 64 + wf0 * 4);
    pw1 = *(const float4*)(W1 + (size_t)wr1 * 64 + wf1 * 4);

    for (int kc = 0; kc < 256; kc += 32) {
        __syncthreads();
        sxT[xf0 * 4 + 0][xr0] = px0.x;
        sxT[xf0 * 4 + 1][xr0] = px0.y;
        sxT[xf0 * 4 + 2][xr0] = px0.z;
        sxT[xf0 * 4 + 3][xr0] = px0.w;
        sxT[xf1 * 4 + 0][xr1] = px1.x;
        sxT[xf1 * 4 + 1][xr1] = px1.y;
        sxT[xf1 * 4 + 2][xr1] = px1.z;
        sxT[xf1 * 4 + 3][xr1] = px1.w;
        *(float4*)&sW[wr0][wf0 * 4] = pw0;
        *(float4*)&sW[wr1][wf1 * 4] = pw1;
        __syncthreads();

        if (kc + 32 < 256) {   // prefetch next K-step before compute
            int kn = kc + 32;
            px0 = (nx0 < NN) ? *(const float4*)(x + (size_t)nx0 * FIN + kn + xf0 * 4)
                             : make_float4(0.f, 0.f, 0.f, 0.f);
            px1 = (nx1 < NN) ? *(const float4*)(x + (size_t)nx1 * FIN + kn + xf1 * 4)
                             : make_float4(0.f, 0.f, 0.f, 0.f);
            pw0 = *(const float4*)(W1 + (size_t)(kn + wr0) * 64 + wf0 * 4);
            pw1 = *(const float4*)(W1 + (size_t)(kn + wr1) * 64 + wf1 * 4);
        }

        #pragma unroll
        for (int k = 0; k < 32; ++k) {
            float4 a = *(const float4*)&sxT[k][tr * 4];
            float4 b = *(const float4*)&sW[k][tc * 4];
            acc[0][0] += a.x * b.x; acc[0][1] += a.x * b.y; acc[0][2] += a.x * b.z; acc[0][3] += a.x * b.w;
            acc[1][0] += a.y * b.x; acc[1][1] += a.y * b.y; acc[1][2] += a.y * b.z; acc[1][3] += a.y * b.w;
            acc[2][0] += a.z * b.x; acc[2][1] += a.z * b.y; acc[2][2] += a.z * b.z; acc[2][3] += a.z * b.w;
            acc[3][0] += a.w * b.x; acc[3][1] += a.w * b.y; acc[3][2] += a.w * b.z; acc[3][3] += a.w * b.w;
        }
    }

    #pragma unroll
    for (int j = 0; j < 4; ++j) {
        int n = n0 + tr * 4 + j;
        if (n < NN) {
            ushort4 v = make_ushort4(f2bf(acc[j][0]), f2bf(acc[j][1]), f2bf(acc[j][2]), f2bf(acc[j][3]));
            *(ushort4*)(h1b + (size_t)n * 64 + tc * 4) = v;
        }
    }

    float sa[4], da[4];
    #pragma unroll
    for (int u = 0; u < 4; ++u) { sa[u] = a1s[tc * 4 + u]; da[u] = a1d[tc * 4 + u]; }
    #pragma unroll
    for (int j = 0; j < 4; ++j) {
        float vs = acc[j][0] * sa[0] + acc[j][1] * sa[1] + acc[j][2] * sa[2] + acc[j][3] * sa[3];
        float vd = acc[j][0] * da[0] + acc[j][1] * da[1] + acc[j][2] * da[2] + acc[j][3] * da[3];
        vs += __shfl_xor(vs, 1, 64);
        vd += __shfl_xor(vd, 1, 64);
        int n = n0 + tr * 4 + j;
        if (!(tc & 1) && n < NN) {
            al1s[n * 8 + (tc >> 1)] = vs;
            al1d[n * 8 + (tc >> 1)] = vd;
        }
    }
}

// ---------- layer 1 aggregation: 4 edges x 16 lanes, uint2 value loads ----------
__global__ __launch_bounds__(256) void k_agg1(
    const int* __restrict__ row, const int* __restrict__ adj,
    const float* __restrict__ al1s, const float* __restrict__ al1d,
    const unsigned* __restrict__ h1b2, const float* __restrict__ b1,
    unsigned* __restrict__ h1e2)
{
    const int wv = threadIdx.x >> 6, lane = threadIdx.x & 63;
    const int n = blockIdx.x * 4 + wv;
    const int q = lane >> 4;           // edge slot in 4-pack
    const int r = lane & 15;           // channel quad -> channels 4r..4r+3
    const int h = r >> 1;              // head
    const float ald = al1d[n * 8 + h];
    const int r0 = row[n], r1 = row[n + 1];

    float dsum = 0.f, ax = 0.f, ay = 0.f, bx = 0.f, by = 0.f;
    for (int c0 = r0; c0 < r1; c0 += 64) {
        int li = c0 + lane;
        int adjv = adj[li < r1 ? li : r0];      // chunk preload, coalesced
        int m = r1 - c0; if (m > 64) m = 64;
        int k = 0;
        for (; k + 16 <= m; k += 16) {
            int s0 = __shfl(adjv, k + 0  + q, 64);
            int s1 = __shfl(adjv, k + 4  + q, 64);
            int s2 = __shfl(adjv, k + 8  + q, 64);
            int s3 = __shfl(adjv, k + 12 + q, 64);
            float a0 = al1s[s0 * 8 + h];
            float a1 = al1s[s1 * 8 + h];
            float a2 = al1s[s2 * 8 + h];
            float a3 = al1s[s3 * 8 + h];
            uint2 u0 = *(const uint2*)(h1b2 + s0 * 32 + r * 2);
            uint2 u1 = *(const uint2*)(h1b2 + s1 * 32 + r * 2);
            uint2 u2 = *(const uint2*)(h1b2 + s2 * 32 + r * 2);
            uint2 u3 = *(const uint2*)(h1b2 + s3 * 32 + r * 2);
            float w0 = __expf(lrelu(a0 + ald));
            float w1 = __expf(lrelu(a1 + ald));
            float w2 = __expf(lrelu(a2 + ald));
            float w3 = __expf(lrelu(a3 + ald));
            dsum += (w0 + w1) + (w2 + w3);
            ax += w0 * bflo(u0.x) + w1 * bflo(u1.x) + w2 * bflo(u2.x) + w3 * bflo(u3.x);
            ay += w0 * bfhi(u0.x) + w1 * bfhi(u1.x) + w2 * bfhi(u2.x) + w3 * bfhi(u3.x);
            bx += w0 * bflo(u0.y) + w1 * bflo(u1.y) + w2 * bflo(u2.y) + w3 * bflo(u3.y);
            by += w0 * bfhi(u0.y) + w1 * bfhi(u1.y) + w2 * bfhi(u2.y) + w3 * bfhi(u3.y);
        }
        for (; k < m; k += 4) {
            int kk = k + q;
            bool act = kk < m;
            int s0 = __shfl(adjv, act ? kk : 0, 64);
            float w0 = act ? __expf(lrelu(al1s[s0 * 8 + h] + ald)) : 0.f;
            uint2 u0 = *(const uint2*)(h1b2 + s0 * 32 + r * 2);
            dsum += w0;
            ax += w0 * bflo(u0.x);
            ay += w0 * bfhi(u0.x);
            bx += w0 * bflo(u0.y);
            by += w0 * bfhi(u0.y);
        }
    }
    // reduce across the 4 edge-slot quarters
    dsum += __shfl_xor(dsum, 16, 64); dsum += __shfl_xor(dsum, 32, 64);
    ax   += __shfl_xor(ax,   16, 64); ax   += __shfl_xor(ax,   32, 64);
    ay   += __shfl_xor(ay,   16, 64); ay   += __shfl_xor(ay,   32, 64);
    bx   += __shfl_xor(bx,   16, 64); bx   += __shfl_xor(bx,   32, 64);
    by   += __shfl_xor(by,   16, 64); by   += __shfl_xor(by,   32, 64);

    float inv = 1.f / dsum;
    float v0 = ax * inv + b1[r * 4 + 0];
    float v1 = ay * inv + b1[r * 4 + 1];
    float v2 = bx * inv + b1[r * 4 + 2];
    float v3 = by * inv + b1[r * 4 + 3];
    v0 = v0 > 0.f ? v0 : __expf(v0) - 1.f;   // ELU fused
    v1 = v1 > 0.f ? v1 : __expf(v1) - 1.f;
    v2 = v2 > 0.f ? v2 : __expf(v2) - 1.f;
    v3 = v3 > 0.f ? v3 : __expf(v3) - 1.f;
    if (q == 0) {
        uint2 o;
        o.x = (unsigned)f2bf(v0) | ((unsigned)f2bf(v1) << 16);
        o.y = (unsigned)f2bf(v2) | ((unsigned)f2bf(v3) << 16);
        *(uint2*)(h1e2 + n * 32 + r * 2) = o;
    }
}

// ---------- layer 2 GEMM: h2b = bf16(h1e @ W2), al2s/al2d logits ----------
__global__ __launch_bounds__(256) void k_gemm2(
    const unsigned short* __restrict__ h1e, const float* __restrict__ W2,
    const float* __restrict__ a2s, const float* __restrict__ a2d,
    unsigned short* __restrict__ h2b, float* __restrict__ al2s, float* __restrict__ al2d)
{
    __shared__ float sW[64 * 16];
    const int t = threadIdx.x;
    for (int i = t; i < 64 * 16; i += 256) sW[i] = W2[i];
    __syncthreads();
    const int n = blockIdx.x * 16 + (t >> 4);
    const int k = t & 15;
    if (n >= NN) return;
    const unsigned short* hr = h1e + (size_t)n * 64;
    float acc = 0.f;
    #pragma unroll
    for (int c = 0; c < 64; ++c) acc += bf2f(hr[c]) * sW[c * 16 + k];
    h2b[(size_t)n * 16 + k] = f2bf(acc);
    float vs = acc * a2s[k], vd = acc * a2d[k];
    #pragma unroll
    for (int off = 1; off < 16; off <<= 1) {
        vs += __shfl_xor(vs, off, 64);
        vd += __shfl_xor(vd, off, 64);
    }
    if (k == 0) { al2s[n] = vs; al2d[n] = vd; }
}

// ---------- layer 2 aggregation: 16 edges x 4 lanes, uint2 value loads ----------
__global__ __launch_bounds__(256) void k_agg2(
    const int* __restrict__ row, const int* __restrict__ adj,
    const float* __restrict__ al2s, const float* __restrict__ al2d,
    const unsigned* __restrict__ h2b2, const float* __restrict__ b2,
    float* __restrict__ out)
{
    const int wv = threadIdx.x >> 6, lane = threadIdx.x & 63;
    const int n = blockIdx.x * 4 + wv;
    const float ald = al2d[n];
    const int r0 = row[n], r1 = row[n + 1];

    const int j = lane >> 2;    // edge slot 0..15
    const int r = lane & 3;     // channel quad -> channels 4r..4r+3
    float dsum = 0.f, ax = 0.f, ay = 0.f, bx = 0.f, by = 0.f;
    for (int i = r0; i < r1; i += 16) {
        int i0 = i + j;
        bool act = i0 < r1;
        int s = adj[act ? i0 : r0];
        float w = act ? __expf(lrelu(al2s[s] + ald)) : 0.f;
        uint2 u = *(const uint2*)(h2b2 + s * 8 + r * 2);
        dsum += w;
        ax += w * bflo(u.x);
        ay += w * bfhi(u.x);
        bx += w * bflo(u.y);
        by += w * bfhi(u.y);
    }
    #pragma unroll
    for (int off = 4; off < 64; off <<= 1) {
        dsum += __shfl_xor(dsum, off, 64);
        ax   += __shfl_xor(ax,   off, 64);
        ay   += __shfl_xor(ay,   off, 64);
        bx   += __shfl_xor(bx,   off, 64);
        by   += __shfl_xor(by,   off, 64);
    }
    float inv = 1.f / dsum;
    float v0 = ax * inv + b2[r * 4 + 0];
    float v1 = ay * inv + b2[r * 4 + 1];
    float v2 = bx * inv + b2[r * 4 + 2];
    float v3 = by * inv + b2[r * 4 + 3];

    // log_softmax over 16 channels = 4 lanes x 4
    float mx = fmaxf(fmaxf(v0, v1), fmaxf(v2, v3));
    mx = fmaxf(mx, __shfl_xor(mx, 1, 64));
    mx = fmaxf(mx, __shfl_xor(mx, 2, 64));
    float se = __expf(v0 - mx) + __expf(v1 - mx) + __expf(v2 - mx) + __expf(v3 - mx);
    se += __shfl_xor(se, 1, 64);
    se += __shfl_xor(se, 2, 64);
    float ls = mx + __logf(se);
    if (j == 0)
        *(float4*)(out + (size_t)n * 16 + r * 4) = make_float4(v0 - ls, v1 - ls, v2 - ls, v3 - ls);
}

extern "C" void kernel_launch(void* const* d_in, const int* in_sizes, int n_in,
                              void* d_out, int out_size, void* d_ws, size_t ws_size,
                              hipStream_t stream)
{
    const float* x    = (const float*)d_in[0];
    const int*   eidx = (const int*)d_in[1];
    const float* W1   = (const float*)d_in[2];
    const float* a1s  = (const float*)d_in[3];
    const float* a1d  = (const float*)d_in[4];
    const float* b1   = (const float*)d_in[5];
    const float* W2   = (const float*)d_in[6];
    const float* a2s  = (const float*)d_in[7];
    const float* a2d  = (const float*)d_in[8];
    const float* b2   = (const float*)d_in[9];
    float* out = (float*)d_out;
    float* ws  = (float*)d_ws;

    const int* esrc = eidx;
    const int* edst = eidx + EE;

    int* gcnt = (int*)(ws + OFF_GCNT);
    int* base = (int*)(ws + OFF_BASE);
    int* row  = (int*)(ws + OFF_ROW);
    unsigned* bkt = (unsigned*)(ws + OFF_BKT);
    int* adj  = (int*)(ws + OFF_ADJ);
    unsigned short* h1b = (unsigned short*)(ws + OFF_H1B);
    unsigned short* h1e = (unsigned short*)(ws + OFF_H1E);
    float* al1s  = ws + OFF_AL1S;
    float* al1d  = ws + OFF_AL1D;
    unsigned short* h2b = (unsigned short*)(ws + OFF_H2B);
    float* al2s  = ws + OFF_AL2S;
    float* al2d  = ws + OFF_AL2D;

    hipMemsetAsync(gcnt, 0, 392 * sizeof(int), stream);

    k_binA <<<NABLK, 256, 0, stream>>>(esrc, edst, gcnt, bkt);
    k_scanB<<<1,     512, 0, stream>>>(gcnt, base, row);
    k_binC <<<NBKT,  256, 0, stream>>>(gcnt, base, bkt, row, adj);

    k_gemm1<<<(NN + 63) / 64, 256, 0, stream>>>(x, W1, a1s, a1d, h1b, al1s, al1d);
    k_agg1 <<<NN / 4, 256, 0, stream>>>(row, adj, al1s, al1d, (const unsigned*)h1b, b1, (unsigned*)h1e);
    k_gemm2<<<NN / 16, 256, 0, stream>>>(h1e, W2, a2s, a2d, h2b, al2s, al2d);
    k_agg2 <<<NN / 4, 256, 0, stream>>>(row, adj, al2s, al2d, (const unsigned*)h2b, b2, out);
}

// Round 11
// 355.345 us; speedup vs baseline: 1.2166x; 1.0629x over previous
//
#include <hip/hip_runtime.h>
#include <math.h>

#define NN   100000
#define EE   1600000
#define FIN  256
#define NCLS 16
#define NEG  0.2f

#define NEDGE (EE + NN)     // with self-loops
#define WBKT  256           // dsts per bucket
#define NBKT  ((NN + WBKT - 1) / WBKT)   // 391
#define CAP   5120          // per-bucket capacity (mean 4352)
#define ABLK  4096          // edges per binA block
#define NABLK ((NEDGE + ABLK - 1) / ABLK)  // 416
#define NGBLK ((NN + 63) / 64)             // 1563 gemm1 blocks

// ---- workspace layout (4-byte element offsets) ----
#define OFF_GCNT  0                          // [392] zeroed each call
#define OFF_BASE  392                        // [392]
#define OFF_ROW   784                        // [NN+1]
#define OFF_BKT   100788                     // [NBKT*CAP] packed (src<<8)|dlow
#define OFF_ADJ   (OFF_BKT + NBKT*CAP)       // [NEDGE]
#define OFF_H1B   (OFF_ADJ + NEDGE)          // [NN*64] bf16 (pre-attn values)
#define OFF_H1E   (OFF_H1B + NN*32)          // [NN*64] bf16 (post-ELU)
#define OFF_AL1S  (OFF_H1E + NN*32)          // [NN*8]
#define OFF_AL1D  (OFF_AL1S + NN*8)          // [NN*8]
#define OFF_H2B   (OFF_AL1D + NN*8)          // [NN*16] bf16
#define OFF_AL2S  (OFF_H2B + NN*8)           // [NN]
#define OFF_AL2D  (OFF_AL2S + NN)            // [NN]

__device__ __forceinline__ float lrelu(float x) { return x >= 0.f ? x : NEG * x; }
__device__ __forceinline__ unsigned short f2bf(float x) {
    unsigned u = __float_as_uint(x);
    return (unsigned short)((u + 0x7FFF + ((u >> 16) & 1)) >> 16);   // RNE
}
__device__ __forceinline__ float bf2f(unsigned short b) {
    return __uint_as_float(((unsigned)b) << 16);
}
__device__ __forceinline__ float bflo(unsigned u) { return __uint_as_float(u << 16); }
__device__ __forceinline__ float bfhi(unsigned u) { return __uint_as_float(u & 0xFFFF0000u); }

// ---------- FUSED: CSR binA (blocks 0..NABLK-1) || layer-1 GEMM (rest) ----------
// binA and gemm1 have no data dependence (binA: edges->bkt; gemm1: x,W1->h1b).
// 1979 total blocks ~ all co-resident on 256 CUs -> the atomic/scatter-bound
// binA overlaps the FMA-bound gemm1 instead of serializing. Bodies unchanged.
__global__ __launch_bounds__(256) void k_binA_gemm1(
    const int* __restrict__ esrc, const int* __restrict__ edst,
    int* __restrict__ gcnt, unsigned* __restrict__ bkt,
    const float* __restrict__ x, const float* __restrict__ W1,
    const float* __restrict__ a1s, const float* __restrict__ a1d,
    unsigned short* __restrict__ h1b, float* __restrict__ al1s, float* __restrict__ al1d)
{
    const int t = threadIdx.x;
    if (blockIdx.x < NABLK) {
        // ---- binA role ----
        __shared__ int lcnt[NBKT];
        __shared__ int lbase[NBKT];
        const int e0 = blockIdx.x * ABLK;
        for (int i = t; i < NBKT; i += 256) lcnt[i] = 0;
        __syncthreads();

        unsigned wrd[16];
        unsigned short bb[16], ll[16];
        #pragma unroll
        for (int j = 0; j < 16; ++j) {
            int ei = e0 + j * 256 + t;
            bb[j] = 0xFFFFu;
            if (ei < NEDGE) {
                int s, d;
                if (ei < EE) { s = esrc[ei]; d = edst[ei]; } else { s = d = ei - EE; }
                int b = d >> 8;
                wrd[j] = ((unsigned)s << 8) | (unsigned)(d & 255);
                bb[j] = (unsigned short)b;
                ll[j] = (unsigned short)atomicAdd(&lcnt[b], 1);
            }
        }
        __syncthreads();
        for (int i = t; i < NBKT; i += 256)
            lbase[i] = lcnt[i] ? atomicAdd(&gcnt[i], lcnt[i]) : 0;
        __syncthreads();
        #pragma unroll
        for (int j = 0; j < 16; ++j) {
            if (bb[j] != 0xFFFFu) {
                int b = bb[j];
                bkt[(size_t)b * CAP + lbase[b] + ll[j]] = wrd[j];
            }
        }
        return;
    }

    // ---- gemm1 role ----
    __shared__ float sxT[32][68];
    __shared__ float sW[32][64];
    const int n0 = (blockIdx.x - NABLK) * 64;
    const int tr = t >> 4, tc = t & 15;

    // per-thread load coordinates
    const int xr0 = t >> 3,         xf0 = t & 7;          // it=0 x
    const int xr1 = (t + 256) >> 3, xf1 = (t + 256) & 7;  // it=1 x
    const int wr0 = t >> 4,         wf0 = t & 15;         // it=0 W
    const int wr1 = (t + 256) >> 4, wf1 = (t + 256) & 15; // it=1 W
    const int nx0 = n0 + xr0, nx1 = n0 + xr1;

    float acc[4][4] = {};
    float4 px0, px1, pw0, pw1;

    // prefetch kc = 0
    px0 = (nx0 < NN) ? *(const float4*)(x + (size_t)nx0 * FIN + xf0 * 4)
                     : make_float4(0.f, 0.f, 0.f, 0.f);
    px1 = (nx1 < NN) ? *(const float4*)(x + (size_t)nx1 * FIN + xf1 * 4)
                     : make_float4(0.f, 0.f, 0.f, 0.f);
    pw0 = *(const float4*)(W1 + (size_t)wr0 * 64 + wf0 * 4);
    pw1 = *(const float4*)(W1 + (size_t)wr1 * 64 + wf1 * 4);

    for (int kc = 0; kc < 256; kc += 32) {
        __syncthreads();
        sxT[xf0 * 4 + 0][xr0] = px0.x;
        sxT[xf0 * 4 + 1][xr0] = px0.y;
        sxT[xf0 * 4 + 2][xr0] = px0.z;
        sxT[xf0 * 4 + 3][xr0] = px0.w;
        sxT[xf1 * 4 + 0][xr1] = px1.x;
        sxT[xf1 * 4 + 1][xr1] = px1.y;
        sxT[xf1 * 4 + 2][xr1] = px1.z;
        sxT[xf1 * 4 + 3][xr1] = px1.w;
        *(float4*)&sW[wr0][wf0 * 4] = pw0;
        *(float4*)&sW[wr1][wf1 * 4] = pw1;
        __syncthreads();

        if (kc + 32 < 256) {   // prefetch next K-step before compute
            int kn = kc + 32;
            px0 = (nx0 < NN) ? *(const float4*)(x + (size_t)nx0 * FIN + kn + xf0 * 4)
                             : make_float4(0.f, 0.f, 0.f, 0.f);
            px1 = (nx1 < NN) ? *(const float4*)(x + (size_t)nx1 * FIN + kn + xf1 * 4)
                             : make_float4(0.f, 0.f, 0.f, 0.f);
            pw0 = *(const float4*)(W1 + (size_t)(kn + wr0) * 64 + wf0 * 4);
            pw1 = *(const float4*)(W1 + (size_t)(kn + wr1) * 64 + wf1 * 4);
        }

        #pragma unroll
        for (int k = 0; k < 32; ++k) {
            float4 a = *(const float4*)&sxT[k][tr * 4];
            float4 b = *(const float4*)&sW[k][tc * 4];
            acc[0][0] += a.x * b.x; acc[0][1] += a.x * b.y; acc[0][2] += a.x * b.z; acc[0][3] += a.x * b.w;
            acc[1][0] += a.y * b.x; acc[1][1] += a.y * b.y; acc[1][2] += a.y * b.z; acc[1][3] += a.y * b.w;
            acc[2][0] += a.z * b.x; acc[2][1] += a.z * b.y; acc[2][2] += a.z * b.z; acc[2][3] += a.z * b.w;
            acc[3][0] += a.w * b.x; acc[3][1] += a.w * b.y; acc[3][2] += a.w * b.z; acc[3][3] += a.w * b.w;
        }
    }

    #pragma unroll
    for (int j = 0; j < 4; ++j) {
        int n = n0 + tr * 4 + j;
        if (n < NN) {
            ushort4 v = make_ushort4(f2bf(acc[j][0]), f2bf(acc[j][1]), f2bf(acc[j][2]), f2bf(acc[j][3]));
            *(ushort4*)(h1b + (size_t)n * 64 + tc * 4) = v;
        }
    }

    float sa[4], da[4];
    #pragma unroll
    for (int u = 0; u < 4; ++u) { sa[u] = a1s[tc * 4 + u]; da[u] = a1d[tc * 4 + u]; }
    #pragma unroll
    for (int j = 0; j < 4; ++j) {
        float vs = acc[j][0] * sa[0] + acc[j][1] * sa[1] + acc[j][2] * sa[2] + acc[j][3] * sa[3];
        float vd = acc[j][0] * da[0] + acc[j][1] * da[1] + acc[j][2] * da[2] + acc[j][3] * da[3];
        vs += __shfl_xor(vs, 1, 64);
        vd += __shfl_xor(vd, 1, 64);
        int n = n0 + tr * 4 + j;
        if (!(tc & 1) && n < NN) {
            al1s[n * 8 + (tc >> 1)] = vs;
            al1d[n * 8 + (tc >> 1)] = vd;
        }
    }
}

// ---------- CSR build, phase B: scan bucket counts -> bases ----------
__global__ __launch_bounds__(512) void k_scanB(
    const int* __restrict__ gcnt, int* __restrict__ base, int* __restrict__ row)
{
    __shared__ int s[512];
    int t = threadIdx.x;
    int v = (t < NBKT) ? gcnt[t] : 0;
    s[t] = v;
    __syncthreads();
    for (int off = 1; off < 512; off <<= 1) {
        int u = (t >= off) ? s[t - off] : 0;
        __syncthreads();
        s[t] += u;
        __syncthreads();
    }
    if (t <= NBKT) base[t] = s[t] - v;   // exclusive; base[NBKT] = NEDGE
    if (t == 0) row[NN] = NEDGE;
}

// ---------- CSR build, phase C: per-bucket local sort -> row + adj ----------
__global__ __launch_bounds__(256) void k_binC(
    const int* __restrict__ gcnt, const int* __restrict__ base,
    const unsigned* __restrict__ bkt, int* __restrict__ row, int* __restrict__ adj)
{
    __shared__ unsigned wd[CAP];          // 20 KB stage
    __shared__ int hist[256], pref[256], cnt2[256];
    const int g = blockIdx.x, t = threadIdx.x;
    const int cn = gcnt[g], bs = base[g];
    hist[t] = 0; cnt2[t] = 0;
    __syncthreads();
    for (int i = t; i < cn; i += 256) {
        unsigned w = bkt[(size_t)g * CAP + i];
        wd[i] = w;
        atomicAdd(&hist[w & 255], 1);
    }
    __syncthreads();
    int v = hist[t];
    pref[t] = v;
    __syncthreads();
    for (int off = 1; off < 256; off <<= 1) {
        int u = (t >= off) ? pref[t - off] : 0;
        __syncthreads();
        pref[t] += u;
        __syncthreads();
    }
    int ex = pref[t] - v;                 // exclusive local prefix
    int n = g * 256 + t;
    if (n < NN) row[n] = bs + ex;
    pref[t] = ex;
    __syncthreads();
    for (int i = t; i < cn; i += 256) {
        unsigned w = wd[i];
        int dl = w & 255;
        int p = atomicAdd(&cnt2[dl], 1);
        adj[bs + pref[dl] + p] = (int)(w >> 8);
    }
}

// ---------- layer 1 aggregation: 4 edges x 16 lanes, uint2 value loads ----------
__global__ __launch_bounds__(256) void k_agg1(
    const int* __restrict__ row, const int* __restrict__ adj,
    const float* __restrict__ al1s, const float* __restrict__ al1d,
    const unsigned* __restrict__ h1b2, const float* __restrict__ b1,
    unsigned* __restrict__ h1e2)
{
    const int wv = threadIdx.x >> 6, lane = threadIdx.x & 63;
    const int n = blockIdx.x * 4 + wv;
    const int q = lane >> 4;           // edge slot in 4-pack
    const int r = lane & 15;           // channel quad -> channels 4r..4r+3
    const int h = r >> 1;              // head
    const float ald = al1d[n * 8 + h];
    const int r0 = row[n], r1 = row[n + 1];

    float dsum = 0.f, ax = 0.f, ay = 0.f, bx = 0.f, by = 0.f;
    for (int c0 = r0; c0 < r1; c0 += 64) {
        int li = c0 + lane;
        int adjv = adj[li < r1 ? li : r0];      // chunk preload, coalesced
        int m = r1 - c0; if (m > 64) m = 64;
        int k = 0;
        for (; k + 16 <= m; k += 16) {
            int s0 = __shfl(adjv, k + 0  + q, 64);
            int s1 = __shfl(adjv, k + 4  + q, 64);
            int s2 = __shfl(adjv, k + 8  + q, 64);
            int s3 = __shfl(adjv, k + 12 + q, 64);
            float a0 = al1s[s0 * 8 + h];
            float a1 = al1s[s1 * 8 + h];
            float a2 = al1s[s2 * 8 + h];
            float a3 = al1s[s3 * 8 + h];
            uint2 u0 = *(const uint2*)(h1b2 + s0 * 32 + r * 2);
            uint2 u1 = *(const uint2*)(h1b2 + s1 * 32 + r * 2);
            uint2 u2 = *(const uint2*)(h1b2 + s2 * 32 + r * 2);
            uint2 u3 = *(const uint2*)(h1b2 + s3 * 32 + r * 2);
            float w0 = __expf(lrelu(a0 + ald));
            float w1 = __expf(lrelu(a1 + ald));
            float w2 = __expf(lrelu(a2 + ald));
            float w3 = __expf(lrelu(a3 + ald));
            dsum += (w0 + w1) + (w2 + w3);
            ax += w0 * bflo(u0.x) + w1 * bflo(u1.x) + w2 * bflo(u2.x) + w3 * bflo(u3.x);
            ay += w0 * bfhi(u0.x) + w1 * bfhi(u1.x) + w2 * bfhi(u2.x) + w3 * bfhi(u3.x);
            bx += w0 * bflo(u0.y) + w1 * bflo(u1.y) + w2 * bflo(u2.y) + w3 * bflo(u3.y);
            by += w0 * bfhi(u0.y) + w1 * bfhi(u1.y) + w2 * bfhi(u2.y) + w3 * bfhi(u3.y);
        }
        for (; k < m; k += 4) {
            int kk = k + q;
            bool act = kk < m;
            int s0 = __shfl(adjv, act ? kk : 0, 64);
            float w0 = act ? __expf(lrelu(al1s[s0 * 8 + h] + ald)) : 0.f;
            uint2 u0 = *(const uint2*)(h1b2 + s0 * 32 + r * 2);
            dsum += w0;
            ax += w0 * bflo(u0.x);
            ay += w0 * bfhi(u0.x);
            bx += w0 * bflo(u0.y);
            by += w0 * bfhi(u0.y);
        }
    }
    // reduce across the 4 edge-slot quarters
    dsum += __shfl_xor(dsum, 16, 64); dsum += __shfl_xor(dsum, 32, 64);
    ax   += __shfl_xor(ax,   16, 64); ax   += __shfl_xor(ax,   32, 64);
    ay   += __shfl_xor(ay,   16, 64); ay   += __shfl_xor(ay,   32, 64);
    bx   += __shfl_xor(bx,   16, 64); bx   += __shfl_xor(bx,   32, 64);
    by   += __shfl_xor(by,   16, 64); by   += __shfl_xor(by,   32, 64);

    float inv = 1.f / dsum;
    float v0 = ax * inv + b1[r * 4 + 0];
    float v1 = ay * inv + b1[r * 4 + 1];
    float v2 = bx * inv + b1[r * 4 + 2];
    float v3 = by * inv + b1[r * 4 + 3];
    v0 = v0 > 0.f ? v0 : __expf(v0) - 1.f;   // ELU fused
    v1 = v1 > 0.f ? v1 : __expf(v1) - 1.f;
    v2 = v2 > 0.f ? v2 : __expf(v2) - 1.f;
    v3 = v3 > 0.f ? v3 : __expf(v3) - 1.f;
    if (q == 0) {
        uint2 o;
        o.x = (unsigned)f2bf(v0) | ((unsigned)f2bf(v1) << 16);
        o.y = (unsigned)f2bf(v2) | ((unsigned)f2bf(v3) << 16);
        *(uint2*)(h1e2 + n * 32 + r * 2) = o;
    }
}

// ---------- layer 2 GEMM: h2b = bf16(h1e @ W2), al2s/al2d logits ----------
__global__ __launch_bounds__(256) void k_gemm2(
    const unsigned short* __restrict__ h1e, const float* __restrict__ W2,
    const float* __restrict__ a2s, const float* __restrict__ a2d,
    unsigned short* __restrict__ h2b, float* __restrict__ al2s, float* __restrict__ al2d)
{
    __shared__ float sW[64 * 16];
    const int t = threadIdx.x;
    for (int i = t; i < 64 * 16; i += 256) sW[i] = W2[i];
    __syncthreads();
    const int n = blockIdx.x * 16 + (t >> 4);
    const int k = t & 15;
    if (n >= NN) return;
    const unsigned short* hr = h1e + (size_t)n * 64;
    float acc = 0.f;
    #pragma unroll
    for (int c = 0; c < 64; ++c) acc += bf2f(hr[c]) * sW[c * 16 + k];
    h2b[(size_t)n * 16 + k] = f2bf(acc);
    float vs = acc * a2s[k], vd = acc * a2d[k];
    #pragma unroll
    for (int off = 1; off < 16; off <<= 1) {
        vs += __shfl_xor(vs, off, 64);
        vd += __shfl_xor(vd, off, 64);
    }
    if (k == 0) { al2s[n] = vs; al2d[n] = vd; }
}

// ---------- layer 2 aggregation: 16 edges x 4 lanes, uint2 value loads ----------
__global__ __launch_bounds__(256) void k_agg2(
    const int* __restrict__ row, const int* __restrict__ adj,
    const float* __restrict__ al2s, const float* __restrict__ al2d,
    const unsigned* __restrict__ h2b2, const float* __restrict__ b2,
    float* __restrict__ out)
{
    const int wv = threadIdx.x >> 6, lane = threadIdx.x & 63;
    const int n = blockIdx.x * 4 + wv;
    const float ald = al2d[n];
    const int r0 = row[n], r1 = row[n + 1];

    const int j = lane >> 2;    // edge slot 0..15
    const int r = lane & 3;     // channel quad -> channels 4r..4r+3
    float dsum = 0.f, ax = 0.f, ay = 0.f, bx = 0.f, by = 0.f;
    for (int i = r0; i < r1; i += 16) {
        int i0 = i + j;
        bool act = i0 < r1;
        int s = adj[act ? i0 : r0];
        float w = act ? __expf(lrelu(al2s[s] + ald)) : 0.f;
        uint2 u = *(const uint2*)(h2b2 + s * 8 + r * 2);
        dsum += w;
        ax += w * bflo(u.x);
        ay += w * bfhi(u.x);
        bx += w * bflo(u.y);
        by += w * bfhi(u.y);
    }
    #pragma unroll
    for (int off = 4; off < 64; off <<= 1) {
        dsum += __shfl_xor(dsum, off, 64);
        ax   += __shfl_xor(ax,   off, 64);
        ay   += __shfl_xor(ay,   off, 64);
        bx   += __shfl_xor(bx,   off, 64);
        by   += __shfl_xor(by,   off, 64);
    }
    float inv = 1.f / dsum;
    float v0 = ax * inv + b2[r * 4 + 0];
    float v1 = ay * inv + b2[r * 4 + 1];
    float v2 = bx * inv + b2[r * 4 + 2];
    float v3 = by * inv + b2[r * 4 + 3];

    // log_softmax over 16 channels = 4 lanes x 4
    float mx = fmaxf(fmaxf(v0, v1), fmaxf(v2, v3));
    mx = fmaxf(mx, __shfl_xor(mx, 1, 64));
    mx = fmaxf(mx, __shfl_xor(mx, 2, 64));
    float se = __expf(v0 - mx) + __expf(v1 - mx) + __expf(v2 - mx) + __expf(v3 - mx);
    se += __shfl_xor(se, 1, 64);
    se += __shfl_xor(se, 2, 64);
    float ls = mx + __logf(se);
    if (j == 0)
        *(float4*)(out + (size_t)n * 16 + r * 4) = make_float4(v0 - ls, v1 - ls, v2 - ls, v3 - ls);
}

extern "C" void kernel_launch(void* const* d_in, const int* in_sizes, int n_in,
                              void* d_out, int out_size, void* d_ws, size_t ws_size,
                              hipStream_t stream)
{
    const float* x    = (const float*)d_in[0];
    const int*   eidx = (const int*)d_in[1];
    const float* W1   = (const float*)d_in[2];
    const float* a1s  = (const float*)d_in[3];
    const float* a1d  = (const float*)d_in[4];
    const float* b1   = (const float*)d_in[5];
    const float* W2   = (const float*)d_in[6];
    const float* a2s  = (const float*)d_in[7];
    const float* a2d  = (const float*)d_in[8];
    const float* b2   = (const float*)d_in[9];
    float* out = (float*)d_out;
    float* ws  = (float*)d_ws;

    const int* esrc = eidx;
    const int* edst = eidx + EE;

    int* gcnt = (int*)(ws + OFF_GCNT);
    int* base = (int*)(ws + OFF_BASE);
    int* row  = (int*)(ws + OFF_ROW);
    unsigned* bkt = (unsigned*)(ws + OFF_BKT);
    int* adj  = (int*)(ws + OFF_ADJ);
    unsigned short* h1b = (unsigned short*)(ws + OFF_H1B);
    unsigned short* h1e = (unsigned short*)(ws + OFF_H1E);
    float* al1s  = ws + OFF_AL1S;
    float* al1d  = ws + OFF_AL1D;
    unsigned short* h2b = (unsigned short*)(ws + OFF_H2B);
    float* al2s  = ws + OFF_AL2S;
    float* al2d  = ws + OFF_AL2D;

    hipMemsetAsync(gcnt, 0, 392 * sizeof(int), stream);

    k_binA_gemm1<<<NABLK + NGBLK, 256, 0, stream>>>(esrc, edst, gcnt, bkt,
                                                    x, W1, a1s, a1d, h1b, al1s, al1d);
    k_scanB<<<1,    512, 0, stream>>>(gcnt, base, row);
    k_binC <<<NBKT, 256, 0, stream>>>(gcnt, base, bkt, row, adj);

    k_agg1 <<<NN / 4, 256, 0, stream>>>(row, adj, al1s, al1d, (const unsigned*)h1b, b1, (unsigned*)h1e);
    k_gemm2<<<NN / 16, 256, 0, stream>>>(h1e, W2, a2s, a2d, h2b, al2s, al2d);
    k_agg2 <<<NN / 4, 256, 0, stream>>>(row, adj, al2s, al2d, (const unsigned*)h2b, b2, out);
}